// Round 1
// 786.113 us; speedup vs baseline: 1.0117x; 1.0117x over previous
//
#include <hip/hip_runtime.h>

#define D 128
#define BD (D * D) // 16384

typedef float v4f __attribute__((ext_vector_type(4)));

__global__ __launch_bounds__(256) void arccos_hess_kernel(
    const float* __restrict__ z1, const float* __restrict__ z2,
    float* __restrict__ out, int B) {
    const int b = blockIdx.x;
    const int t = threadIdx.x;

    __shared__ float u1[D], u2[D];
    __shared__ float ws1[4], ws2[4], ws12[4];

    // ---- Phase 1: norms + dot ----
    float v1 = 0.f, v2 = 0.f;
    if (t < D) {
        v1 = z1[(size_t)b * D + t];
        v2 = z2[(size_t)b * D + t];
    }
    float s1 = v1 * v1, s2 = v2 * v2, s12 = v1 * v2;
#pragma unroll
    for (int off = 32; off > 0; off >>= 1) {
        s1  += __shfl_down(s1, off, 64);
        s2  += __shfl_down(s2, off, 64);
        s12 += __shfl_down(s12, off, 64);
    }
    const int wave = t >> 6, lane = t & 63;
    if (lane == 0) { ws1[wave] = s1; ws2[wave] = s2; ws12[wave] = s12; }
    __syncthreads();

    const float n1sq = ws1[0] + ws1[1] + ws1[2] + ws1[3];
    const float n2sq = ws2[0] + ws2[1] + ws2[2] + ws2[3];
    const float dot  = ws12[0] + ws12[1] + ws12[2] + ws12[3];
    const float n1 = sqrtf(n1sq), n2 = sqrtf(n2sq);
    const float inv11 = 1.0f / n1sq;
    const float inv22 = 1.0f / n2sq;
    const float inv12 = 1.0f / (n1 * n2);
    const float c  = dot * inv12;
    const float c3 = 3.0f * c;

    if (t < D) {
        u1[t] = v1 / n1;
        u2[t] = v2 / n2;
    }
    __syncthreads();

    // ---- Phase 2: write 3 * 128x128 matrices ----
    // thread t owns column group j0 = (t&31)*4 (fixed -> register float4),
    // and rows i = (t>>5) + 8k for k in 0..15.
    const int j0 = (t & 31) << 2;
    const float uj1[4] = { u1[j0], u1[j0 + 1], u1[j0 + 2], u1[j0 + 3] };
    const float uj2[4] = { u2[j0], u2[j0 + 1], u2[j0 + 2], u2[j0 + 3] };

    float* out0 = out + (size_t)b * BD;
    float* out1 = out0 + (size_t)B * BD;
    float* out2 = out1 + (size_t)B * BD;

#pragma unroll
    for (int k = 0; k < 16; ++k) {
        const int i = (t >> 5) + (k << 3);
        const float a1 = u1[i]; // broadcast within half-wave (free)
        const float a2 = u2[i];

        v4f h11, h12, h22;
#pragma unroll
        for (int q = 0; q < 4; ++q) {
            const float b1 = uj1[q], b2 = uj2[q];
            const float o11 = a1 * b1;
            const float o12 = a1 * b2;
            const float o21 = a2 * b1;
            const float o22 = a2 * b2;
            const float s1221 = o12 + o21;
            const float diag = (i == j0 + q) ? 1.0f : 0.0f;
            h11[q] = (s1221 - c3 * o11 + c * diag) * inv11;
            h12[q] = (o11 + o22 - c * o21 - diag) * inv12;
            h22[q] = (s1221 - c3 * o22 + c * diag) * inv22;
        }
        const size_t off = (size_t)i * D + j0;
        // A/B vs previous round: plain (through-L2 write-back) stores instead
        // of nontemporal. Fill kernel proves this path streams at 6.25 TB/s.
        *(v4f*)(out0 + off) = h11;
        *(v4f*)(out1 + off) = h12;
        *(v4f*)(out2 + off) = h22;
    }
}

extern "C" void kernel_launch(void* const* d_in, const int* in_sizes, int n_in,
                              void* d_out, int out_size, void* d_ws, size_t ws_size,
                              hipStream_t stream) {
    const float* z1 = (const float*)d_in[0];
    const float* z2 = (const float*)d_in[1];
    float* out = (float*)d_out;
    const int B = in_sizes[0] / D; // 4096
    arccos_hess_kernel<<<B, 256, 0, stream>>>(z1, z2, out, B);
}